// Round 6
// baseline (762.902 us; speedup 1.0000x reference)
//
#include <hip/hip_runtime.h>

#define QDIM 4096
#define NDIM 50000
#define KDIM 1024
#define DDIM 256
#define QBLK 64                  // query 64-row tiles
#define EBLK 782                 // ceil(NDIM/64) entity tiles
#define TBLK (QBLK + EBLK)       // 846
#define TAU 0.3f                 // refine margin ~14 sigma of fp16 screen noise
#define REF_GRID 128
#define GSPAN 8192

typedef _Float16 half8 __attribute__((ext_vector_type(8)));
typedef float    f32x4 __attribute__((ext_vector_type(4)));

// ---- emulate numpy pairwise sum of squares for n=256 (two 128-halves, 8 accumulators)
__device__ float np_pairwise_sq(const float* a) {
#pragma clang fp contract(off)
    float res[2];
    for (int h = 0; h < 2; ++h) {
        const float* p = a + h * 128;
        float r0 = p[0] * p[0], r1 = p[1] * p[1], r2 = p[2] * p[2], r3 = p[3] * p[3];
        float r4 = p[4] * p[4], r5 = p[5] * p[5], r6 = p[6] * p[6], r7 = p[7] * p[7];
        for (int i = 8; i < 128; i += 8) {
            r0 += p[i + 0] * p[i + 0];
            r1 += p[i + 1] * p[i + 1];
            r2 += p[i + 2] * p[i + 2];
            r3 += p[i + 3] * p[i + 3];
            r4 += p[i + 4] * p[i + 4];
            r5 += p[i + 5] * p[i + 5];
            r6 += p[i + 6] * p[i + 6];
            r7 += p[i + 7] * p[i + 7];
        }
        res[h] = ((r0 + r1) + (r2 + r3)) + ((r4 + r5) + (r6 + r7));
    }
    return res[0] + res[1];
}

// ---------------------------------------------------------------- prep+cvt: c2np[k], codebook->fp16, zero refCtr
__global__ __launch_bounds__(64) void prepcvt_kernel(const float* __restrict__ cb,
                                                     _Float16* __restrict__ cbh,
                                                     float* __restrict__ c2np,
                                                     int* __restrict__ refCtr) {
    int k = blockIdx.x;
    int t = threadIdx.x;
    const float* src = cb + (size_t)k * DDIM + t * 4;
    float4 v = *(const float4*)src;
    _Float16* dst = cbh + (size_t)k * DDIM + t * 4;
    dst[0] = (_Float16)v.x; dst[1] = (_Float16)v.y;
    dst[2] = (_Float16)v.z; dst[3] = (_Float16)v.w;
    if (t == 0) {
        c2np[k] = np_pairwise_sq(cb + (size_t)k * DDIM);
        if (k == 0) *refCtr = 0;
    }
}

// ==================== LDS swizzle: element d of row r lives at 16B-slot (d>>3)^(r&7) ====================
// Round-4 K-loop structure (CHUNK=64, stage-direct-to-LDS, 32 MFMAs per barrier gap) — verbatim;
// only the isQ branch (write S vs argmin-update) differs per block.

__global__ __launch_bounds__(256) void fused16_kernel(const float* __restrict__ Q,
                                                      const float* __restrict__ E,
                                                      const _Float16* __restrict__ CBH,
                                                      const float* __restrict__ c2,
                                                      float* __restrict__ S,
                                                      int* __restrict__ idxOut,
                                                      float* __restrict__ idxF,
                                                      float* __restrict__ lossPart,
                                                      int* __restrict__ refCtr,
                                                      int* __restrict__ refList) {
    __shared__ _Float16 As[64 * 256];
    __shared__ _Float16 Bs[64 * 256];
    __shared__ float xsq[64];
    __shared__ float rowd2s[64];
    int tid = threadIdx.x;
    int lane = tid & 63;
    int w = tid >> 6;                 // wave -> rows w*16..w*16+15
    int blk = blockIdx.x;
    bool isQ = blk < QBLK;
    int rowBase = isQ ? blk * 64 : (blk - QBLK) * 64;
    const float* M = isQ ? Q : E;

    // ---- stage A rows f32 -> fp16 swizzled (+ ||x||^2 for entity)
    {
        int r = tid >> 2, seg = tid & 3;
        int rg = rowBase + r;
        if (!isQ && rg >= NDIM) rg = NDIM - 1;
        const float* src = M + (size_t)rg * DDIM + seg * 64;
        float x2p = 0.f;
#pragma unroll
        for (int i = 0; i < 8; ++i) {
            float4 v0 = *(const float4*)&src[i * 8];
            float4 v1 = *(const float4*)&src[i * 8 + 4];
            x2p += v0.x * v0.x + v0.y * v0.y + v0.z * v0.z + v0.w * v0.w;
            x2p += v1.x * v1.x + v1.y * v1.y + v1.z * v1.z + v1.w * v1.w;
            half8 h;
            h[0] = (_Float16)v0.x; h[1] = (_Float16)v0.y; h[2] = (_Float16)v0.z; h[3] = (_Float16)v0.w;
            h[4] = (_Float16)v1.x; h[5] = (_Float16)v1.y; h[6] = (_Float16)v1.z; h[7] = (_Float16)v1.w;
            int slot = (seg * 8 + i) ^ (r & 7);
            *(half8*)&As[r * 256 + slot * 8] = h;
        }
        if (!isQ) {
            x2p += __shfl_down(x2p, 2, 4);
            x2p += __shfl_down(x2p, 1, 4);
            if (seg == 0) xsq[r] = x2p;
        }
    }
    __syncthreads();

    // ---- A fragments live in registers for all 16 chunks
    half8 a[8];
    int g = lane >> 4;
    {
        int rA = w * 16 + (lane & 15);
#pragma unroll
        for (int s8 = 0; s8 < 8; ++s8) {
            int slot = (s8 * 4 + g) ^ (rA & 7);
            a[s8] = *(half8*)&As[rA * 256 + slot * 8];
        }
    }

    float m1[4] = {1e30f, 1e30f, 1e30f, 1e30f};
    float m2[4] = {1e30f, 1e30f, 1e30f, 1e30f};
    int   mi[4] = {0, 0, 0, 0};

    for (int kc = 0; kc < 16; ++kc) {
        __syncthreads();              // everyone done reading Bs from prev chunk
        {   // stage B chunk (64 codes) fp16 global -> LDS swizzled (direct, compiler-scheduled)
            int c = tid >> 2, seg = tid & 3;
            const _Float16* src = CBH + (size_t)(kc * 64 + c) * DDIM + seg * 64;
#pragma unroll
            for (int i = 0; i < 8; ++i) {
                half8 v = *(const half8*)&src[i * 8];
                int slot = (seg * 8 + i) ^ (c & 7);
                *(half8*)&Bs[c * 256 + slot * 8] = v;
            }
        }
        float cc[4];
        if (!isQ) {
#pragma unroll
            for (int t = 0; t < 4; ++t) cc[t] = c2[kc * 64 + t * 16 + (lane & 15)];
        }
        __syncthreads();

#pragma unroll
        for (int t = 0; t < 4; ++t) {
            f32x4 acc = {0.f, 0.f, 0.f, 0.f};
            int cB = t * 16 + (lane & 15);
#pragma unroll
            for (int s8 = 0; s8 < 8; ++s8) {
                int slot = (s8 * 4 + g) ^ (cB & 7);
                half8 b = *(half8*)&Bs[cB * 256 + slot * 8];
                acc = __builtin_amdgcn_mfma_f32_16x16x32_f16(a[s8], b, acc, 0, 0, 0);
            }
            int ki = kc * 64 + cB;
            if (isQ) {
#pragma unroll
                for (int j = 0; j < 4; ++j) {
                    int row = rowBase + w * 16 + g * 4 + j;
                    S[(size_t)row * KDIM + ki] = acc[j];
                }
            } else {
#pragma unroll
                for (int j = 0; j < 4; ++j) {
                    float v = cc[t] - 2.0f * acc[j];
                    if (v < m1[j]) { m2[j] = m1[j]; m1[j] = v; mi[j] = ki; }
                    else if (v < m2[j]) { m2[j] = v; }
                }
            }
        }
    }
    if (isQ) return;                  // block-uniform

    // ---- entity epilogue: reduce (min1, idx, min2) across 16-lane col groups
#pragma unroll
    for (int j = 0; j < 4; ++j) {
        for (int m = 8; m >= 1; m >>= 1) {
            float ov  = __shfl_xor(m1[j], m, 16);
            int   oi  = __shfl_xor(mi[j], m, 16);
            float ov2 = __shfl_xor(m2[j], m, 16);
            if (ov < m1[j] || (ov == m1[j] && oi < mi[j])) {
                m2[j] = fminf(m1[j], ov2);
                m1[j] = ov; mi[j] = oi;
            } else {
                m2[j] = fminf(m2[j], ov);
            }
        }
    }
    if ((lane & 15) == 0) {
#pragma unroll
        for (int j = 0; j < 4; ++j) {
            int rloc = w * 16 + (lane >> 4) * 4 + j;
            int row = rowBase + rloc;
            if (row < NDIM) {
                idxOut[row] = mi[j];
                idxF[row] = (float)mi[j];
                rowd2s[rloc] = xsq[rloc] + m1[j];
                if (m2[j] - m1[j] < TAU) {     // ambiguous under fp16 noise -> np-exact re-argmin
                    int p = atomicAdd(refCtr, 1);
                    refList[p] = row;
                }
            } else {
                rowd2s[rloc] = 0.f;
            }
        }
    }
    __syncthreads();
    if (tid == 0) {
        float s = 0.f;
        for (int i = 0; i < 64; ++i) s += rowd2s[i];
        lossPart[blk - QBLK] = s;
    }
}

// ---------------------------------------------------------------- np-f32-exact re-argmin, 8 rows/block + fused loss
__global__ __launch_bounds__(256) void refine8_kernel(const float* __restrict__ E,
                                                      const float* __restrict__ CB,
                                                      const float* __restrict__ c2np,
                                                      const int* __restrict__ refCtr,
                                                      const int* __restrict__ refList,
                                                      int* __restrict__ idxOut,
                                                      float* __restrict__ idxF,
                                                      const float* __restrict__ lossPart,
                                                      float* __restrict__ lossOut) {
    __shared__ float xrows[8][DDIM];
    __shared__ float x2sh[8];
    int tid = threadIdx.x;
    if (blockIdx.x == REF_GRID - 1 && tid < 64) {   // fused loss finalize (fixed-order)
        float s = 0.f;
        for (int i = tid; i < EBLK; i += 64) s += lossPart[i];
        for (int m = 32; m >= 1; m >>= 1) s += __shfl_down(s, m, 64);
        if (tid == 0) lossOut[0] = 1.25f * s / (float)(NDIM * DDIM);
    }
    int count = *refCtr;
    if (count > NDIM) count = NDIM;
    int rl = tid >> 5;          // row slot 0..7
    int c0 = tid & 31;          // code phase
    for (int base = blockIdx.x * 8; base < count; base += REF_GRID * 8) {
        int nr = count - base; if (nr > 8) nr = 8;
        int myRow = refList[base + (rl < nr ? rl : 0)];
        {   // stage 8 rows
            const float* src = E + (size_t)myRow * DDIM + c0 * 8;
            *(float4*)&xrows[rl][c0 * 8]     = *(const float4*)&src[0];
            *(float4*)&xrows[rl][c0 * 8 + 4] = *(const float4*)&src[4];
        }
        __syncthreads();
        if (tid < 8) x2sh[tid] = np_pairwise_sq(&xrows[tid][0]);
        __syncthreads();
        float best = 1e30f;
        int bidx = 0x7fffffff;
        const float* xr = &xrows[rl][0];
        for (int j = 0; j < 32; j += 4) {    // 4-way ILP on the sequential-FMA chains
            const float* p0 = CB + (size_t)(c0 + (j + 0) * 32) * DDIM;
            const float* p1 = CB + (size_t)(c0 + (j + 1) * 32) * DDIM;
            const float* p2 = CB + (size_t)(c0 + (j + 2) * 32) * DDIM;
            const float* p3 = CB + (size_t)(c0 + (j + 3) * 32) * DDIM;
            float d0 = 0.f, d1 = 0.f, d2 = 0.f, d3 = 0.f;
            for (int d = 0; d < DDIM; ++d) {
                float x = xr[d];
                d0 = __builtin_fmaf(p0[d], x, d0);
                d1 = __builtin_fmaf(p1[d], x, d1);
                d2 = __builtin_fmaf(p2[d], x, d2);
                d3 = __builtin_fmaf(p3[d], x, d3);
            }
            float dv[4] = {d0, d1, d2, d3};
#pragma unroll
            for (int u = 0; u < 4; ++u) {    // ascending code order -> first-min tiebreak
                int c = c0 + (j + u) * 32;
                float v = (x2sh[rl] + c2np[c]) - 2.0f * dv[u];
                if (v < best) { best = v; bidx = c; }
            }
        }
        for (int m = 16; m >= 1; m >>= 1) {
            float ov = __shfl_xor(best, m, 32);
            int   oi = __shfl_xor(bidx, m, 32);
            if (ov < best || (ov == best && oi < bidx)) { best = ov; bidx = oi; }
        }
        if (c0 == 0 && rl < nr) {
            int row = refList[base + rl];
            idxOut[row] = bidx;
            idxF[row] = (float)bidx;
        }
        __syncthreads();
    }
}

// ---------------------------------------------------------------- score[q][n] = S[q][idx[n]]  (819 MB streaming write)
__global__ __launch_bounds__(256) void gather_kernel(const float* __restrict__ S,
                                                     const int* __restrict__ idx,
                                                     float* __restrict__ score) {
    __shared__ float Srow[4 * 1024];
    int tid = threadIdx.x;
    int qBase = blockIdx.y * 4;
    int nBase = blockIdx.x * GSPAN;
#pragma unroll
    for (int i = 0; i < 4; ++i) {
        int o = (tid + i * 256) * 4;
        *(float4*)&Srow[o] = *(const float4*)&S[(size_t)qBase * KDIM + o];
    }
    __syncthreads();
#pragma unroll
    for (int s = 0; s < 8; ++s) {
        int n = nBase + s * 1024 + tid * 4;
        if (n < NDIM) {
            int4 id = *(const int4*)&idx[n];
#pragma unroll
            for (int q = 0; q < 4; ++q) {
                const float* sp = &Srow[q * 1024];
                float4 v = make_float4(sp[id.x], sp[id.y], sp[id.z], sp[id.w]);
                *(float4*)&score[(size_t)(qBase + q) * NDIM + n] = v;
            }
        }
    }
}

extern "C" void kernel_launch(void* const* d_in, const int* in_sizes, int n_in,
                              void* d_out, int out_size, void* d_ws, size_t ws_size,
                              hipStream_t stream) {
    const float* query  = (const float*)d_in[0];
    const float* entity = (const float*)d_in[1];
    const float* cb     = (const float*)d_in[2];
    float* out = (float*)d_out;
    char* ws = (char*)d_ws;

    float*     S        = (float*)ws;                   // 16,777,216 B
    float*     c2np     = (float*)(ws + 16777216);      //      4,096 B
    int*       idxW     = (int*)  (ws + 16781312);      //    200,000 B
    int*       refCtr   = (int*)  (ws + 16981312);      //          4 B
    int*       refList  = (int*)  (ws + 16981316);      //    200,000 B
    float*     lossPart = (float*)(ws + 17181316);      //      3,128 B
    _Float16*  cbh      = (_Float16*)(ws + 17184448);   //    524,288 B

    size_t QN = (size_t)QDIM * NDIM;
    float* score   = out;
    float* lossOut = out + QN;
    float* idxF    = out + QN + 1;

    prepcvt_kernel<<<dim3(KDIM), dim3(64), 0, stream>>>(cb, cbh, c2np, refCtr);
    fused16_kernel<<<dim3(TBLK), dim3(256), 0, stream>>>(query, entity, cbh, c2np, S,
                                                         idxW, idxF, lossPart, refCtr, refList);
    refine8_kernel<<<dim3(REF_GRID), dim3(256), 0, stream>>>(entity, cb, c2np, refCtr, refList,
                                                             idxW, idxF, lossPart, lossOut);
    gather_kernel<<<dim3((NDIM + GSPAN - 1) / GSPAN, QDIM / 4), dim3(256), 0, stream>>>(S, idxW, score);
}

// Round 7
// 490.099 us; speedup vs baseline: 1.5566x; 1.5566x over previous
//
#include <hip/hip_runtime.h>

#define QDIM 4096
#define NDIM 50000
#define KDIM 1024
#define DDIM 256
#define NBLK 782          // ceil(NDIM/64)
#define TAU  0.3f         // refine margin: ~16 sigma of the fp16 screen noise

typedef _Float16 half8 __attribute__((ext_vector_type(8)));
typedef float    f32x4 __attribute__((ext_vector_type(4)));

// ---- emulate numpy pairwise sum of squares for n=256 (two 128-halves, 8 accumulators)
__device__ float np_pairwise_sq(const float* a) {
#pragma clang fp contract(off)
    float res[2];
    for (int h = 0; h < 2; ++h) {
        const float* p = a + h * 128;
        float r0 = p[0] * p[0], r1 = p[1] * p[1], r2 = p[2] * p[2], r3 = p[3] * p[3];
        float r4 = p[4] * p[4], r5 = p[5] * p[5], r6 = p[6] * p[6], r7 = p[7] * p[7];
        for (int i = 8; i < 128; i += 8) {
            r0 += p[i + 0] * p[i + 0];
            r1 += p[i + 1] * p[i + 1];
            r2 += p[i + 2] * p[i + 2];
            r3 += p[i + 3] * p[i + 3];
            r4 += p[i + 4] * p[i + 4];
            r5 += p[i + 5] * p[i + 5];
            r6 += p[i + 6] * p[i + 6];
            r7 += p[i + 7] * p[i + 7];
        }
        res[h] = ((r0 + r1) + (r2 + r3)) + ((r4 + r5) + (r6 + r7));
    }
    return res[0] + res[1];
}

// ---------------------------------------------------------------- prep: c2np[k] (np-emulated), zero refCtr
__global__ __launch_bounds__(256) void prep_kernel(const float* __restrict__ cb,
                                                   float* __restrict__ c2np,
                                                   int* __restrict__ refCtr) {
    int k = blockIdx.x * 256 + threadIdx.x;
    if (k < KDIM) c2np[k] = np_pairwise_sq(cb + (size_t)k * DDIM);
    if (k == 0) *refCtr = 0;
}

// ---------------------------------------------------------------- codebook f32 -> fp16
__global__ __launch_bounds__(64) void cvt_kernel(const float* __restrict__ cb,
                                                 _Float16* __restrict__ cbh) {
    int k = blockIdx.x;
    int t = threadIdx.x;
    const float* src = cb + (size_t)k * DDIM + t * 4;
    _Float16* dst = cbh + (size_t)k * DDIM + t * 4;
    float4 v = *(const float4*)src;
    dst[0] = (_Float16)v.x; dst[1] = (_Float16)v.y;
    dst[2] = (_Float16)v.z; dst[3] = (_Float16)v.w;
}

// ==================== shared staging helpers (swizzle: 16B slot ^= row&7) ====================
// LDS layout per row: 256 halves = 32 slots of 8 halves; element d lives at
// slot (d>>3)^(row&7), offset d&7.  Fragment reads: lane&15 = row/col,
// k = (lane>>4)*8 + j within each K=32 slice s8  ->  slot = s8*4 + (lane>>4).

// ---------------------------------------------------------------- screen: fp16-MFMA distance GEMM + argmin(+2nd) + loss
__global__ __launch_bounds__(256) void argmin16_kernel(const float* __restrict__ E,
                                                       const _Float16* __restrict__ CBH,
                                                       const float* __restrict__ c2,
                                                       int* __restrict__ idxOut,
                                                       float* __restrict__ idxF,
                                                       float* __restrict__ lossPart,
                                                       int* __restrict__ refCtr,
                                                       int* __restrict__ refList) {
    __shared__ _Float16 As[64 * 256];
    __shared__ _Float16 Bs[64 * 256];
    __shared__ float xsq[64];
    __shared__ float rowd2s[64];
    int tid = threadIdx.x;
    int lane = tid & 63;
    int w = tid >> 6;                 // wave -> rows w*16..w*16+15
    int rowBase = blockIdx.x * 64;

    // ---- stage A (entity rows) f32 -> fp16 swizzled, accumulate ||x||^2 in f32
    {
        int r = tid >> 2, seg = tid & 3;
        int rg = rowBase + r; if (rg >= NDIM) rg = NDIM - 1;
        const float* src = E + (size_t)rg * DDIM + seg * 64;
        float x2p = 0.f;
#pragma unroll
        for (int i = 0; i < 8; ++i) {
            float4 v0 = *(const float4*)&src[i * 8];
            float4 v1 = *(const float4*)&src[i * 8 + 4];
            x2p += v0.x * v0.x + v0.y * v0.y + v0.z * v0.z + v0.w * v0.w;
            x2p += v1.x * v1.x + v1.y * v1.y + v1.z * v1.z + v1.w * v1.w;
            half8 h;
            h[0] = (_Float16)v0.x; h[1] = (_Float16)v0.y; h[2] = (_Float16)v0.z; h[3] = (_Float16)v0.w;
            h[4] = (_Float16)v1.x; h[5] = (_Float16)v1.y; h[6] = (_Float16)v1.z; h[7] = (_Float16)v1.w;
            int slot = (seg * 8 + i) ^ (r & 7);
            *(half8*)&As[r * 256 + slot * 8] = h;
        }
        x2p += __shfl_down(x2p, 2, 4);
        x2p += __shfl_down(x2p, 1, 4);
        if (seg == 0) xsq[r] = x2p;
    }
    __syncthreads();

    // ---- A fragments live in registers for all 16 chunks
    half8 a[8];
    {
        int rA = w * 16 + (lane & 15);
        int g = lane >> 4;
#pragma unroll
        for (int s8 = 0; s8 < 8; ++s8) {
            int slot = (s8 * 4 + g) ^ (rA & 7);
            a[s8] = *(half8*)&As[rA * 256 + slot * 8];
        }
    }

    float m1[4] = {1e30f, 1e30f, 1e30f, 1e30f};
    float m2[4] = {1e30f, 1e30f, 1e30f, 1e30f};
    int   mi[4] = {0, 0, 0, 0};

    for (int kc = 0; kc < 16; ++kc) {
        __syncthreads();              // everyone done reading Bs from prev chunk
        {   // stage B chunk (64 codes) fp16 global -> LDS swizzled
            int c = tid >> 2, seg = tid & 3;
            const _Float16* src = CBH + (size_t)(kc * 64 + c) * DDIM + seg * 64;
#pragma unroll
            for (int i = 0; i < 8; ++i) {
                half8 v = *(const half8*)&src[i * 8];
                int slot = (seg * 8 + i) ^ (c & 7);
                *(half8*)&Bs[c * 256 + slot * 8] = v;
            }
        }
        float cc[4];
#pragma unroll
        for (int t = 0; t < 4; ++t) cc[t] = c2[kc * 64 + t * 16 + (lane & 15)];
        __syncthreads();

        int g = lane >> 4;
#pragma unroll
        for (int t = 0; t < 4; ++t) {
            f32x4 acc = {0.f, 0.f, 0.f, 0.f};
            int cB = t * 16 + (lane & 15);
#pragma unroll
            for (int s8 = 0; s8 < 8; ++s8) {
                int slot = (s8 * 4 + g) ^ (cB & 7);
                half8 b = *(half8*)&Bs[cB * 256 + slot * 8];
                acc = __builtin_amdgcn_mfma_f32_16x16x32_f16(a[s8], b, acc, 0, 0, 0);
            }
            int ki = kc * 64 + cB;
#pragma unroll
            for (int j = 0; j < 4; ++j) {
                float v = cc[t] - 2.0f * acc[j];
                if (v < m1[j]) { m2[j] = m1[j]; m1[j] = v; mi[j] = ki; }
                else if (v < m2[j]) { m2[j] = v; }
            }
        }
    }
    // reduce (min1, idx, min2) across the 16 lanes holding the same rows (cols lane&15)
#pragma unroll
    for (int j = 0; j < 4; ++j) {
        for (int m = 8; m >= 1; m >>= 1) {
            float ov  = __shfl_xor(m1[j], m, 16);
            int   oi  = __shfl_xor(mi[j], m, 16);
            float ov2 = __shfl_xor(m2[j], m, 16);
            if (ov < m1[j] || (ov == m1[j] && oi < mi[j])) {
                m2[j] = fminf(m1[j], ov2);
                m1[j] = ov; mi[j] = oi;
            } else {
                m2[j] = fminf(m2[j], ov);
            }
        }
    }
    if ((lane & 15) == 0) {
#pragma unroll
        for (int j = 0; j < 4; ++j) {
            int rloc = w * 16 + (lane >> 4) * 4 + j;
            int row = rowBase + rloc;
            if (row < NDIM) {
                idxOut[row] = mi[j];
                idxF[row] = (float)mi[j];
                rowd2s[rloc] = xsq[rloc] + m1[j];
                if (m2[j] - m1[j] < TAU) {     // ambiguous under fp16 noise -> np-exact re-argmin
                    int p = atomicAdd(refCtr, 1);
                    refList[p] = row;
                }
            } else {
                rowd2s[rloc] = 0.f;
            }
        }
    }
    __syncthreads();
    if (tid == 0) {
        float s = 0.f;
        for (int i = 0; i < 64; ++i) s += rowd2s[i];
        lossPart[blockIdx.x] = s;
    }
}

// ---------------------------------------------------------------- S = query @ codebook^T via fp16 MFMA, K-split grid (64,8)
__global__ __launch_bounds__(256) void sgemm16_kernel(const float* __restrict__ Q,
                                                      const _Float16* __restrict__ CBH,
                                                      float* __restrict__ S) {
    __shared__ _Float16 As[64 * 256];
    __shared__ _Float16 Bs[64 * 256];
    int tid = threadIdx.x;
    int lane = tid & 63;
    int w = tid >> 6;
    int rowBase = blockIdx.x * 64;
    int kcBase = blockIdx.y * 2;      // each block handles 2 of the 16 K-chunks

    {
        int r = tid >> 2, seg = tid & 3;
        const float* src = Q + (size_t)(rowBase + r) * DDIM + seg * 64;
#pragma unroll
        for (int i = 0; i < 8; ++i) {
            float4 v0 = *(const float4*)&src[i * 8];
            float4 v1 = *(const float4*)&src[i * 8 + 4];
            half8 h;
            h[0] = (_Float16)v0.x; h[1] = (_Float16)v0.y; h[2] = (_Float16)v0.z; h[3] = (_Float16)v0.w;
            h[4] = (_Float16)v1.x; h[5] = (_Float16)v1.y; h[6] = (_Float16)v1.z; h[7] = (_Float16)v1.w;
            int slot = (seg * 8 + i) ^ (r & 7);
            *(half8*)&As[r * 256 + slot * 8] = h;
        }
    }
    __syncthreads();
    half8 a[8];
    {
        int rA = w * 16 + (lane & 15);
        int g = lane >> 4;
#pragma unroll
        for (int s8 = 0; s8 < 8; ++s8) {
            int slot = (s8 * 4 + g) ^ (rA & 7);
            a[s8] = *(half8*)&As[rA * 256 + slot * 8];
        }
    }

    for (int kci = 0; kci < 2; ++kci) {
        int kc = kcBase + kci;
        __syncthreads();
        {
            int c = tid >> 2, seg = tid & 3;
            const _Float16* src = CBH + (size_t)(kc * 64 + c) * DDIM + seg * 64;
#pragma unroll
            for (int i = 0; i < 8; ++i) {
                half8 v = *(const half8*)&src[i * 8];
                int slot = (seg * 8 + i) ^ (c & 7);
                *(half8*)&Bs[c * 256 + slot * 8] = v;
            }
        }
        __syncthreads();

        int g = lane >> 4;
#pragma unroll
        for (int t = 0; t < 4; ++t) {
            f32x4 acc = {0.f, 0.f, 0.f, 0.f};
            int cB = t * 16 + (lane & 15);
#pragma unroll
            for (int s8 = 0; s8 < 8; ++s8) {
                int slot = (s8 * 4 + g) ^ (cB & 7);
                half8 b = *(half8*)&Bs[cB * 256 + slot * 8];
                acc = __builtin_amdgcn_mfma_f32_16x16x32_f16(a[s8], b, acc, 0, 0, 0);
            }
#pragma unroll
            for (int j = 0; j < 4; ++j) {
                int row = rowBase + w * 16 + g * 4 + j;
                S[(size_t)row * KDIM + kc * 64 + cB] = acc[j];
            }
        }
    }
}

// ---------------------------------------------------------------- np-f32-exact re-argmin for flagged rows
__global__ __launch_bounds__(256) void refine_kernel(const float* __restrict__ E,
                                                     const float* __restrict__ CB,
                                                     const float* __restrict__ c2np,
                                                     const int* __restrict__ refCtr,
                                                     const int* __restrict__ refList,
                                                     int* __restrict__ idxOut,
                                                     float* __restrict__ idxF) {
    __shared__ float xrow[DDIM];
    __shared__ float x2sh;
    __shared__ float wval[4];
    __shared__ int widx[4];
    int tid = threadIdx.x;
    int count = *refCtr;
    if (count > NDIM) count = NDIM;
    for (int b = blockIdx.x; b < count; b += gridDim.x) {
        int row = refList[b];
        xrow[tid] = E[(size_t)row * DDIM + tid];
        __syncthreads();
        if (tid == 0) x2sh = np_pairwise_sq(xrow);
        __syncthreads();
        float best = 1e30f;
        int bidx = 0x7fffffff;
#pragma unroll
        for (int kk = 0; kk < 4; ++kk) {
            int k = tid + kk * 256;
            const float* cp = CB + (size_t)k * DDIM;
            float dot = 0.f;                    // BLAS-style sequential FMA in d-order
            for (int d = 0; d < DDIM; ++d) dot = __builtin_fmaf(cp[d], xrow[d], dot);
            float t1 = x2sh + c2np[k];
            float v = t1 - 2.0f * dot;
            if (v < best || (v == best && k < bidx)) { best = v; bidx = k; }
        }
        for (int m = 32; m >= 1; m >>= 1) {
            float ov = __shfl_xor(best, m, 64);
            int   oi = __shfl_xor(bidx, m, 64);
            if (ov < best || (ov == best && oi < bidx)) { best = ov; bidx = oi; }
        }
        if ((tid & 63) == 0) { wval[tid >> 6] = best; widx[tid >> 6] = bidx; }
        __syncthreads();
        if (tid == 0) {
            float bv = wval[0]; int bi = widx[0];
#pragma unroll
            for (int w = 1; w < 4; ++w)
                if (wval[w] < bv || (wval[w] == bv && widx[w] < bi)) { bv = wval[w]; bi = widx[w]; }
            idxOut[row] = bi;
            idxF[row] = (float)bi;
        }
        __syncthreads();
    }
}

// ---------------------------------------------------------------- loss finalize (deterministic fixed-order reduce)
__global__ void loss_kernel(const float* __restrict__ lossPart, float* __restrict__ out) {
    int t = threadIdx.x;
    float s = 0.f;
    for (int i = t; i < NBLK; i += 64) s += lossPart[i];
    for (int m = 32; m >= 1; m >>= 1) s += __shfl_down(s, m, 64);
    if (t == 0) out[0] = 1.25f * s / (float)(NDIM * DDIM);
}

// ---------------------------------------------------------------- score[q][n] = S[q][idx[n]]  (819 MB streaming NT write)
__global__ __launch_bounds__(256) void gather_kernel(const float* __restrict__ S,
                                                     const int* __restrict__ idx,
                                                     float* __restrict__ score) {
    __shared__ float Srow[4 * 1024];
    int tid = threadIdx.x;
    int qBase = blockIdx.y * 4;
    int nBase = blockIdx.x * 2048;
#pragma unroll
    for (int i = 0; i < 4; ++i) {
        int o = (tid + i * 256) * 4;
        *(float4*)&Srow[o] = *(const float4*)&S[(size_t)qBase * KDIM + o];
    }
    __syncthreads();
#pragma unroll
    for (int s = 0; s < 2; ++s) {
        int n = nBase + s * 1024 + tid * 4;
        if (n < NDIM) {
            int4 id = *(const int4*)&idx[n];
#pragma unroll
            for (int q = 0; q < 4; ++q) {
                const float* sp = &Srow[q * 1024];
                f32x4 v = {sp[id.x], sp[id.y], sp[id.z], sp[id.w]};
                __builtin_nontemporal_store(v, (f32x4*)&score[(size_t)(qBase + q) * NDIM + n]);
            }
        }
    }
}

extern "C" void kernel_launch(void* const* d_in, const int* in_sizes, int n_in,
                              void* d_out, int out_size, void* d_ws, size_t ws_size,
                              hipStream_t stream) {
    const float* query  = (const float*)d_in[0];
    const float* entity = (const float*)d_in[1];
    const float* cb     = (const float*)d_in[2];
    float* out = (float*)d_out;
    char* ws = (char*)d_ws;

    float*     S        = (float*)ws;                   // 16,777,216 B
    float*     c2np     = (float*)(ws + 16777216);      //      4,096 B
    int*       idxW     = (int*)  (ws + 16781312);      //    200,000 B
    int*       refCtr   = (int*)  (ws + 16981312);      //          4 B
    int*       refList  = (int*)  (ws + 16981316);      //    200,000 B
    float*     lossPart = (float*)(ws + 17181316);      //      3,128 B
    _Float16*  cbh      = (_Float16*)(ws + 17184448);   //    524,288 B

    size_t QN = (size_t)QDIM * NDIM;
    float* score   = out;
    float* lossOut = out + QN;
    float* idxF    = out + QN + 1;

    prep_kernel<<<dim3(4), dim3(256), 0, stream>>>(cb, c2np, refCtr);
    cvt_kernel<<<dim3(KDIM), dim3(64), 0, stream>>>(cb, cbh);
    sgemm16_kernel<<<dim3(QDIM / 64, 8), dim3(256), 0, stream>>>(query, cbh, S);
    argmin16_kernel<<<dim3(NBLK), dim3(256), 0, stream>>>(entity, cbh, c2np, idxW, idxF,
                                                          lossPart, refCtr, refList);
    refine_kernel<<<dim3(256), dim3(256), 0, stream>>>(entity, cb, c2np, refCtr, refList, idxW, idxF);
    loss_kernel<<<dim3(1), dim3(64), 0, stream>>>(lossPart, lossOut);
    gather_kernel<<<dim3((NDIM + 2047) / 2048, QDIM / 4), dim3(256), 0, stream>>>(S, idxW, score);
}

// Round 8
// 477.627 us; speedup vs baseline: 1.5973x; 1.0261x over previous
//
#include <hip/hip_runtime.h>

#define QDIM 4096
#define NDIM 50000
#define KDIM 1024
#define DDIM 256
#define NBLK 782          // ceil(NDIM/64)
#define TAU  0.3f         // refine margin: ~16 sigma of the fp16 screen noise

typedef _Float16 half8 __attribute__((ext_vector_type(8)));
typedef float    f32x4 __attribute__((ext_vector_type(4)));

// ---- emulate numpy pairwise sum of squares for n=256 (two 128-halves, 8 accumulators)
__device__ float np_pairwise_sq(const float* a) {
#pragma clang fp contract(off)
    float res[2];
    for (int h = 0; h < 2; ++h) {
        const float* p = a + h * 128;
        float r0 = p[0] * p[0], r1 = p[1] * p[1], r2 = p[2] * p[2], r3 = p[3] * p[3];
        float r4 = p[4] * p[4], r5 = p[5] * p[5], r6 = p[6] * p[6], r7 = p[7] * p[7];
        for (int i = 8; i < 128; i += 8) {
            r0 += p[i + 0] * p[i + 0];
            r1 += p[i + 1] * p[i + 1];
            r2 += p[i + 2] * p[i + 2];
            r3 += p[i + 3] * p[i + 3];
            r4 += p[i + 4] * p[i + 4];
            r5 += p[i + 5] * p[i + 5];
            r6 += p[i + 6] * p[i + 6];
            r7 += p[i + 7] * p[i + 7];
        }
        res[h] = ((r0 + r1) + (r2 + r3)) + ((r4 + r5) + (r6 + r7));
    }
    return res[0] + res[1];
}

// ---------------------------------------------------------------- prep: c2np[k] (np-emulated), zero refCtr
__global__ __launch_bounds__(256) void prep_kernel(const float* __restrict__ cb,
                                                   float* __restrict__ c2np,
                                                   int* __restrict__ refCtr) {
    int k = blockIdx.x * 256 + threadIdx.x;
    if (k < KDIM) c2np[k] = np_pairwise_sq(cb + (size_t)k * DDIM);
    if (k == 0) *refCtr = 0;
}

// ---------------------------------------------------------------- codebook f32 -> fp16
__global__ __launch_bounds__(64) void cvt_kernel(const float* __restrict__ cb,
                                                 _Float16* __restrict__ cbh) {
    int k = blockIdx.x;
    int t = threadIdx.x;
    const float* src = cb + (size_t)k * DDIM + t * 4;
    _Float16* dst = cbh + (size_t)k * DDIM + t * 4;
    float4 v = *(const float4*)src;
    dst[0] = (_Float16)v.x; dst[1] = (_Float16)v.y;
    dst[2] = (_Float16)v.z; dst[3] = (_Float16)v.w;
}

// ==================== LDS: ONE 32 KB buffer reused for A-staging then B-chunks ====================
// (A-fragments live in registers for the whole K-loop; keeping a dedicated As
//  buffer would waste 32 KB and halve occupancy: 2 -> 4 blocks/CU.)
// Swizzle: element d of row r lives at 16B-slot (d>>3)^(r&7), offset d&7.
// Fragment reads: lane&15 = row/col, k = (lane>>4)*8+j in K=32 slice s8 -> slot = s8*4+(lane>>4).

// ---------------------------------------------------------------- screen: fp16-MFMA distance GEMM + argmin(+2nd) + loss
__global__ __launch_bounds__(256) void argmin16_kernel(const float* __restrict__ E,
                                                       const _Float16* __restrict__ CBH,
                                                       const float* __restrict__ c2,
                                                       int* __restrict__ idxOut,
                                                       float* __restrict__ idxF,
                                                       float* __restrict__ lossPart,
                                                       int* __restrict__ refCtr,
                                                       int* __restrict__ refList) {
    __shared__ _Float16 Buf[64 * 256];   // 32 KB, reused A then B
    __shared__ float xsq[64];
    __shared__ float rowd2s[64];
    int tid = threadIdx.x;
    int lane = tid & 63;
    int w = tid >> 6;                 // wave -> rows w*16..w*16+15
    int rowBase = blockIdx.x * 64;

    // ---- stage A (entity rows) f32 -> fp16 swizzled, accumulate ||x||^2 in f32
    {
        int r = tid >> 2, seg = tid & 3;
        int rg = rowBase + r; if (rg >= NDIM) rg = NDIM - 1;
        const float* src = E + (size_t)rg * DDIM + seg * 64;
        float x2p = 0.f;
#pragma unroll
        for (int i = 0; i < 8; ++i) {
            float4 v0 = *(const float4*)&src[i * 8];
            float4 v1 = *(const float4*)&src[i * 8 + 4];
            x2p += v0.x * v0.x + v0.y * v0.y + v0.z * v0.z + v0.w * v0.w;
            x2p += v1.x * v1.x + v1.y * v1.y + v1.z * v1.z + v1.w * v1.w;
            half8 h;
            h[0] = (_Float16)v0.x; h[1] = (_Float16)v0.y; h[2] = (_Float16)v0.z; h[3] = (_Float16)v0.w;
            h[4] = (_Float16)v1.x; h[5] = (_Float16)v1.y; h[6] = (_Float16)v1.z; h[7] = (_Float16)v1.w;
            int slot = (seg * 8 + i) ^ (r & 7);
            *(half8*)&Buf[r * 256 + slot * 8] = h;
        }
        x2p += __shfl_down(x2p, 2, 4);
        x2p += __shfl_down(x2p, 1, 4);
        if (seg == 0) xsq[r] = x2p;
    }
    __syncthreads();

    // ---- A fragments live in registers for all 16 chunks
    half8 a[8];
    {
        int rA = w * 16 + (lane & 15);
        int g = lane >> 4;
#pragma unroll
        for (int s8 = 0; s8 < 8; ++s8) {
            int slot = (s8 * 4 + g) ^ (rA & 7);
            a[s8] = *(half8*)&Buf[rA * 256 + slot * 8];
        }
    }

    float m1[4] = {1e30f, 1e30f, 1e30f, 1e30f};
    float m2[4] = {1e30f, 1e30f, 1e30f, 1e30f};
    int   mi[4] = {0, 0, 0, 0};

    for (int kc = 0; kc < 16; ++kc) {
        __syncthreads();              // everyone done reading Buf (A-frags or prev B chunk)
        {   // stage B chunk (64 codes) fp16 global -> LDS swizzled
            int c = tid >> 2, seg = tid & 3;
            const _Float16* src = CBH + (size_t)(kc * 64 + c) * DDIM + seg * 64;
#pragma unroll
            for (int i = 0; i < 8; ++i) {
                half8 v = *(const half8*)&src[i * 8];
                int slot = (seg * 8 + i) ^ (c & 7);
                *(half8*)&Buf[c * 256 + slot * 8] = v;
            }
        }
        float cc[4];
#pragma unroll
        for (int t = 0; t < 4; ++t) cc[t] = c2[kc * 64 + t * 16 + (lane & 15)];
        __syncthreads();

        int g = lane >> 4;
#pragma unroll
        for (int t = 0; t < 4; ++t) {
            f32x4 acc = {0.f, 0.f, 0.f, 0.f};
            int cB = t * 16 + (lane & 15);
#pragma unroll
            for (int s8 = 0; s8 < 8; ++s8) {
                int slot = (s8 * 4 + g) ^ (cB & 7);
                half8 b = *(half8*)&Buf[cB * 256 + slot * 8];
                acc = __builtin_amdgcn_mfma_f32_16x16x32_f16(a[s8], b, acc, 0, 0, 0);
            }
            int ki = kc * 64 + cB;
#pragma unroll
            for (int j = 0; j < 4; ++j) {
                float v = cc[t] - 2.0f * acc[j];
                if (v < m1[j]) { m2[j] = m1[j]; m1[j] = v; mi[j] = ki; }
                else if (v < m2[j]) { m2[j] = v; }
            }
        }
    }
    // reduce (min1, idx, min2) across the 16 lanes holding the same rows (cols lane&15)
#pragma unroll
    for (int j = 0; j < 4; ++j) {
        for (int m = 8; m >= 1; m >>= 1) {
            float ov  = __shfl_xor(m1[j], m, 16);
            int   oi  = __shfl_xor(mi[j], m, 16);
            float ov2 = __shfl_xor(m2[j], m, 16);
            if (ov < m1[j] || (ov == m1[j] && oi < mi[j])) {
                m2[j] = fminf(m1[j], ov2);
                m1[j] = ov; mi[j] = oi;
            } else {
                m2[j] = fminf(m2[j], ov);
            }
        }
    }
    if ((lane & 15) == 0) {
#pragma unroll
        for (int j = 0; j < 4; ++j) {
            int rloc = w * 16 + (lane >> 4) * 4 + j;
            int row = rowBase + rloc;
            if (row < NDIM) {
                idxOut[row] = mi[j];
                idxF[row] = (float)mi[j];
                rowd2s[rloc] = xsq[rloc] + m1[j];
                if (m2[j] - m1[j] < TAU) {     // ambiguous under fp16 noise -> np-exact re-argmin
                    int p = atomicAdd(refCtr, 1);
                    refList[p] = row;
                }
            } else {
                rowd2s[rloc] = 0.f;
            }
        }
    }
    __syncthreads();
    if (tid == 0) {
        float s = 0.f;
        for (int i = 0; i < 64; ++i) s += rowd2s[i];
        lossPart[blockIdx.x] = s;
    }
}

// ---------------------------------------------------------------- S = query @ codebook^T via fp16 MFMA, K-split grid (64,8)
__global__ __launch_bounds__(256) void sgemm16_kernel(const float* __restrict__ Q,
                                                      const _Float16* __restrict__ CBH,
                                                      float* __restrict__ S) {
    __shared__ _Float16 Buf[64 * 256];   // 32 KB, reused A then B
    int tid = threadIdx.x;
    int lane = tid & 63;
    int w = tid >> 6;
    int rowBase = blockIdx.x * 64;
    int kcBase = blockIdx.y * 2;      // each block handles 2 of the 16 K-chunks

    {
        int r = tid >> 2, seg = tid & 3;
        const float* src = Q + (size_t)(rowBase + r) * DDIM + seg * 64;
#pragma unroll
        for (int i = 0; i < 8; ++i) {
            float4 v0 = *(const float4*)&src[i * 8];
            float4 v1 = *(const float4*)&src[i * 8 + 4];
            half8 h;
            h[0] = (_Float16)v0.x; h[1] = (_Float16)v0.y; h[2] = (_Float16)v0.z; h[3] = (_Float16)v0.w;
            h[4] = (_Float16)v1.x; h[5] = (_Float16)v1.y; h[6] = (_Float16)v1.z; h[7] = (_Float16)v1.w;
            int slot = (seg * 8 + i) ^ (r & 7);
            *(half8*)&Buf[r * 256 + slot * 8] = h;
        }
    }
    __syncthreads();
    half8 a[8];
    {
        int rA = w * 16 + (lane & 15);
        int g = lane >> 4;
#pragma unroll
        for (int s8 = 0; s8 < 8; ++s8) {
            int slot = (s8 * 4 + g) ^ (rA & 7);
            a[s8] = *(half8*)&Buf[rA * 256 + slot * 8];
        }
    }

    for (int kci = 0; kci < 2; ++kci) {
        int kc = kcBase + kci;
        __syncthreads();              // done reading Buf (A-frags or prev B chunk)
        {
            int c = tid >> 2, seg = tid & 3;
            const _Float16* src = CBH + (size_t)(kc * 64 + c) * DDIM + seg * 64;
#pragma unroll
            for (int i = 0; i < 8; ++i) {
                half8 v = *(const half8*)&src[i * 8];
                int slot = (seg * 8 + i) ^ (c & 7);
                *(half8*)&Buf[c * 256 + slot * 8] = v;
            }
        }
        __syncthreads();

        int g = lane >> 4;
#pragma unroll
        for (int t = 0; t < 4; ++t) {
            f32x4 acc = {0.f, 0.f, 0.f, 0.f};
            int cB = t * 16 + (lane & 15);
#pragma unroll
            for (int s8 = 0; s8 < 8; ++s8) {
                int slot = (s8 * 4 + g) ^ (cB & 7);
                half8 b = *(half8*)&Buf[cB * 256 + slot * 8];
                acc = __builtin_amdgcn_mfma_f32_16x16x32_f16(a[s8], b, acc, 0, 0, 0);
            }
#pragma unroll
            for (int j = 0; j < 4; ++j) {
                int row = rowBase + w * 16 + g * 4 + j;
                S[(size_t)row * KDIM + kc * 64 + cB] = acc[j];
            }
        }
    }
}

// ---------------------------------------------------------------- np-f32-exact re-argmin for flagged rows
__global__ __launch_bounds__(256) void refine_kernel(const float* __restrict__ E,
                                                     const float* __restrict__ CB,
                                                     const float* __restrict__ c2np,
                                                     const int* __restrict__ refCtr,
                                                     const int* __restrict__ refList,
                                                     int* __restrict__ idxOut,
                                                     float* __restrict__ idxF) {
    __shared__ float xrow[DDIM];
    __shared__ float x2sh;
    __shared__ float wval[4];
    __shared__ int widx[4];
    int tid = threadIdx.x;
    int count = *refCtr;
    if (count > NDIM) count = NDIM;
    for (int b = blockIdx.x; b < count; b += gridDim.x) {
        int row = refList[b];
        xrow[tid] = E[(size_t)row * DDIM + tid];
        __syncthreads();
        if (tid == 0) x2sh = np_pairwise_sq(xrow);
        __syncthreads();
        float best = 1e30f;
        int bidx = 0x7fffffff;
#pragma unroll
        for (int kk = 0; kk < 4; ++kk) {
            int k = tid + kk * 256;
            const float* cp = CB + (size_t)k * DDIM;
            float dot = 0.f;                    // BLAS-style sequential FMA in d-order
            for (int d = 0; d < DDIM; ++d) dot = __builtin_fmaf(cp[d], xrow[d], dot);
            float t1 = x2sh + c2np[k];
            float v = t1 - 2.0f * dot;
            if (v < best || (v == best && k < bidx)) { best = v; bidx = k; }
        }
        for (int m = 32; m >= 1; m >>= 1) {
            float ov = __shfl_xor(best, m, 64);
            int   oi = __shfl_xor(bidx, m, 64);
            if (ov < best || (ov == best && oi < bidx)) { best = ov; bidx = oi; }
        }
        if ((tid & 63) == 0) { wval[tid >> 6] = best; widx[tid >> 6] = bidx; }
        __syncthreads();
        if (tid == 0) {
            float bv = wval[0]; int bi = widx[0];
#pragma unroll
            for (int w = 1; w < 4; ++w)
                if (wval[w] < bv || (wval[w] == bv && widx[w] < bi)) { bv = wval[w]; bi = widx[w]; }
            idxOut[row] = bi;
            idxF[row] = (float)bi;
        }
        __syncthreads();
    }
}

// ---------------------------------------------------------------- loss finalize (deterministic fixed-order reduce)
__global__ void loss_kernel(const float* __restrict__ lossPart, float* __restrict__ out) {
    int t = threadIdx.x;
    float s = 0.f;
    for (int i = t; i < NBLK; i += 64) s += lossPart[i];
    for (int m = 32; m >= 1; m >>= 1) s += __shfl_down(s, m, 64);
    if (t == 0) out[0] = 1.25f * s / (float)(NDIM * DDIM);
}

// ---------------------------------------------------------------- score[q][n] = S[q][idx[n]]  (819 MB streaming NT write)
__global__ __launch_bounds__(256) void gather_kernel(const float* __restrict__ S,
                                                     const int* __restrict__ idx,
                                                     float* __restrict__ score) {
    __shared__ float Srow[4 * 1024];
    int tid = threadIdx.x;
    int qBase = blockIdx.y * 4;
    int nBase = blockIdx.x * 2048;
#pragma unroll
    for (int i = 0; i < 4; ++i) {
        int o = (tid + i * 256) * 4;
        *(float4*)&Srow[o] = *(const float4*)&S[(size_t)qBase * KDIM + o];
    }
    __syncthreads();
#pragma unroll
    for (int s = 0; s < 2; ++s) {
        int n = nBase + s * 1024 + tid * 4;
        if (n < NDIM) {
            int4 id = *(const int4*)&idx[n];
#pragma unroll
            for (int q = 0; q < 4; ++q) {
                const float* sp = &Srow[q * 1024];
                f32x4 v = {sp[id.x], sp[id.y], sp[id.z], sp[id.w]};
                __builtin_nontemporal_store(v, (f32x4*)&score[(size_t)(qBase + q) * NDIM + n]);
            }
        }
    }
}

extern "C" void kernel_launch(void* const* d_in, const int* in_sizes, int n_in,
                              void* d_out, int out_size, void* d_ws, size_t ws_size,
                              hipStream_t stream) {
    const float* query  = (const float*)d_in[0];
    const float* entity = (const float*)d_in[1];
    const float* cb     = (const float*)d_in[2];
    float* out = (float*)d_out;
    char* ws = (char*)d_ws;

    float*     S        = (float*)ws;                   // 16,777,216 B
    float*     c2np     = (float*)(ws + 16777216);      //      4,096 B
    int*       idxW     = (int*)  (ws + 16781312);      //    200,000 B
    int*       refCtr   = (int*)  (ws + 16981312);      //          4 B
    int*       refList  = (int*)  (ws + 16981316);      //    200,000 B
    float*     lossPart = (float*)(ws + 17181316);      //      3,128 B
    _Float16*  cbh      = (_Float16*)(ws + 17184448);   //    524,288 B

    size_t QN = (size_t)QDIM * NDIM;
    float* score   = out;
    float* lossOut = out + QN;
    float* idxF    = out + QN + 1;

    prep_kernel<<<dim3(4), dim3(256), 0, stream>>>(cb, c2np, refCtr);
    cvt_kernel<<<dim3(KDIM), dim3(64), 0, stream>>>(cb, cbh);
    sgemm16_kernel<<<dim3(QDIM / 64, 8), dim3(256), 0, stream>>>(query, cbh, S);
    argmin16_kernel<<<dim3(NBLK), dim3(256), 0, stream>>>(entity, cbh, c2np, idxW, idxF,
                                                          lossPart, refCtr, refList);
    refine_kernel<<<dim3(256), dim3(256), 0, stream>>>(entity, cb, c2np, refCtr, refList, idxW, idxF);
    loss_kernel<<<dim3(1), dim3(64), 0, stream>>>(lossPart, lossOut);
    gather_kernel<<<dim3((NDIM + 2047) / 2048, QDIM / 4), dim3(256), 0, stream>>>(S, idxW, score);
}